// Round 12
// baseline (64.100 us; speedup 1.0000x reference)
//
#include <hip/hip_runtime.h>
#include <math.h>

// Problem constants (from reference)
#define BB 32
#define HH 512
#define WW 512
#define T_STEPS 16
#define DT_C 0.2f
#define HW (HH * WW)        // 262144 elements per sample (C=1)
#define RBLK 16             // reduce blocks per sample

// Temporal fusion parameters (NF=8 steps per dispatch, 2 dispatches)
#define NF 8
#define TSC 64              // output tile cols
#define TSR 128             // output tile rows
#define ITR 146             // input rows: 24 strips x 6 + 2 static halo rows
#define NSLOT 50            // LDS publish rows: static0 + 24x{top,bot} + static145
#define SLOTW 84            // LDS slot stride in floats

// ---------------------------------------------------------------------------
// Round 1: periodic Laplacian is mean-zero and f<0.25 makes each step a
//   convex combination -> y stays in [0,1] EXACTLY (clip no-op mid-run) and
//   D = d_coef*sigmoid(mean(x)) is CONSTANT across steps.
// Round 2: no same-address atomics -> deterministic tree reduce.
// Round 3-8: temporal fusion; register-resident 6x8 strips; NF=8 x 2 passes;
//   LDS reduced to a 50-row publish buffer (ROUND-9 SLOT MAP, proven 52.8us):
//   strip s publishes top->2s+1, bottom->2s+2; reads up from 2s (s=0 -> slot 0
//   = static row 0), down from 2s+3 (s=23 -> slot 49 = static row 145).
// Round 10: (a) never force occupancy via __launch_bounds__ 2nd arg (VGPR
//   clamp -> full strip spill, 7x); (b) coop launch not worth it.
// Round 11 lesson: bundling clampless + slot-remap regressed to 62us; the
//   remap was justified only by the spilling mega kernel's conflict counter
//   (evidence didn't transfer). -> EXACT round-9 structure, ONLY clampless:
//   o = fmaf(f, sum4, g4*c), g4=1-4f (5 VALU ops/cell, was 7); clamp only at
//   the final out write (and t==0 copy).
// Validity after k<=8 steps: rows [k,146-k) -> [8,138) >= out [9,137);
//   cols [k,80-k) -> [8,72) == out cols exactly.
// ---------------------------------------------------------------------------

__device__ __forceinline__ float4 clamp4(float4 v) {
    v.x = fminf(fmaxf(v.x, 0.f), 1.f);
    v.y = fminf(fmaxf(v.y, 0.f), 1.f);
    v.z = fminf(fmaxf(v.z, 0.f), 1.f);
    v.w = fminf(fmaxf(v.w, 0.f), 1.f);
    return v;
}

__device__ __forceinline__ float block_sum_256(float v) {
    __shared__ float lds[4];
#pragma unroll
    for (int off = 32; off > 0; off >>= 1)
        v += __shfl_down(v, off, 64);
    const int lane = threadIdx.x & 63;
    const int wid  = threadIdx.x >> 6;
    if (lane == 0) lds[wid] = v;
    __syncthreads();
    float s = 0.f;
    if (threadIdx.x == 0) s = lds[0] + lds[1] + lds[2] + lds[3];
    return s;
}

// Stage 1: per-block partial sums of x. grid: (RBLK, BB), block: 256.
__global__ __launch_bounds__(256) void reduce_x_kernel(
        const float* __restrict__ x, const int* __restrict__ t,
        float* __restrict__ partials) {
    const int b = blockIdx.y;
    if (t[b] <= 0) return;                 // D unused for t==0 samples
    const float4* xb = (const float4*)(x + (size_t)b * HW);
    float v = 0.f;
    const int base = blockIdx.x * (HW / 4 / RBLK);   // 4096 float4 per block
#pragma unroll
    for (int k = 0; k < 16; k++) {
        float4 c = xb[base + k * 256 + threadIdx.x];
        v += (c.x + c.y) + (c.z + c.w);
    }
    float s = block_sum_256(v);
    if (threadIdx.x == 0) partials[b * RBLK + blockIdx.x] = s;
}

// Fused kernel: up to NF clampless Euler steps, field register-resident
// (6-row x 8-col per thread). grid: (32, BB). block: 256.
__global__ __launch_bounds__(256) void fused_kernel(
        const float* __restrict__ src,   // stencil source buffer
        float* __restrict__ adst,        // destination: still-active samples
        float* __restrict__ fdst,        // destination: finishing samples (== out)
        const float* __restrict__ x,     // original input (t==0 copy, base==0)
        float* __restrict__ out,         // final output (t==0 copy dest)
        const int* __restrict__ t,
        const float* __restrict__ partials,
        const float* __restrict__ dcoef,
        int base) {
    const int b = blockIdx.y;
    const int tb = t[b];
    const int tx = blockIdx.x & 7;       // col tile 0..7
    const int ty = blockIdx.x >> 3;      // row tile 0..3
    const int h0 = ty * TSR;
    const int w0 = tx * TSC;

    if (tb <= base) {
        if (base == 0 && tb == 0) {
            // copy x -> out (clip applied; near-no-op on [0,1) input)
            const float4* s4 = (const float4*)(x + (size_t)b * HW);
            float4* d4 = (float4*)(out + (size_t)b * HW);
            for (int j = threadIdx.x; j < TSR * (TSC / 4); j += 256) {
                const int r = j >> 4, c4 = j & 15;
                const int idx = (h0 + r) * (WW / 4) + (w0 >> 2) + c4;
                d4[idx] = clamp4(s4[idx]);
            }
        }
        return;   // sample finished earlier; data already in out
    }

    int nst = tb - base;
    if (nst > NF) nst = NF;
    const bool finish = (tb <= base + NF);
    float* dstp = finish ? fdst : adst;

    // f computed inline (block-uniform, deterministic sequential sum)
    float psum = 0.f;
#pragma unroll
    for (int k = 0; k < RBLK; k++) psum += partials[b * RBLK + k];
    const float f  = dcoef[0] * (1.0f / (1.0f + expf(-psum * (1.0f / (float)HW)))) * DT_C;
    const float g4 = 1.0f - 4.0f * f;

    __shared__ __align__(16) float pub[NSLOT][SLOTW];

    // ---- lane mapping: 6 strips x 10 col-groups per wave ----
    const int ln  = threadIdx.x & 63;
    const int si  = ln / 10;                 // 0..5 active, 6 = idle-duplicate
    const int g   = ln - si * 10;            // 8-col group 0..9 (0..3 for si=6)
    const bool act = (si < 6);
    const int s   = act ? ((threadIdx.x >> 6) * 6 + si) : 0;  // strip 0..23
    const int r1  = 1 + 6 * s;               // first owned local row
    const int cb  = 8 * (act ? g : 0);       // local col base 0..72

    const float* sb = src + (size_t)b * HW;
    const int gc = (w0 - 8 + cb) & (WW - 1); // global col base (8-aligned)

    // ---- load 6 rows x 8 cols straight into registers ----
    float4 cA[6], cB[6];
#pragma unroll
    for (int j = 0; j < 6; j++) {
        const int gr = (h0 - 9 + r1 + j) & (HH - 1);
        cA[j] = *(const float4*)(sb + gr * WW + gc);
        cB[j] = *(const float4*)(sb + gr * WW + gc + 4);
    }
    // static halo rows 0 and 145 -> slots 0 and NSLOT-1
    if (threadIdx.x < 40) {
        const int r  = threadIdx.x / 20;     // 0: top halo, 1: bottom halo
        const int cg = threadIdx.x % 20;
        const int lr = r ? (ITR - 1) : 0;
        const int gr = (h0 - 9 + lr) & (HH - 1);
        const int gc4 = ((w0 >> 2) - 2 + cg) & (WW / 4 - 1);
        *(float4*)(&pub[r ? (NSLOT - 1) : 0][cg * 4]) =
            *(const float4*)(sb + gr * WW + gc4 * 4);
    }
    // initial publish of strip top/bottom: top->2s+1, bottom->2s+2
    if (act) {
        *(float4*)(&pub[2 * s + 1][cb])     = cA[0];
        *(float4*)(&pub[2 * s + 1][cb + 4]) = cB[0];
        *(float4*)(&pub[2 * s + 2][cb])     = cA[5];
        *(float4*)(&pub[2 * s + 2][cb + 4]) = cB[5];
    }
    __syncthreads();

    // ---- nst clampless register-resident Euler steps (up-carry) ----
    for (int it = 0; it < nst; it++) {
        float4 uA = *(const float4*)(&pub[2 * s][cb]);       // bottom(s-1)
        float4 uB = *(const float4*)(&pub[2 * s][cb + 4]);
        const float4 dA = *(const float4*)(&pub[2 * s + 3][cb]);  // top(s+1)
        const float4 dB = *(const float4*)(&pub[2 * s + 3][cb + 4]);
#pragma unroll
        for (int j = 0; j < 6; j++) {
            const float4 a = cA[j];
            const float4 q = cB[j];
            const float4 nA = (j == 5) ? dA : cA[j + 1];
            const float4 nB = (j == 5) ? dB : cB[j + 1];
            const float L = __shfl_up(q.w, 1, 64);    // lane-1's col cb-1
            const float R = __shfl_down(a.x, 1, 64);  // lane+1's col cb+8
            float4 oA, oB;
            oA.x = fmaf(f, (L   + a.y) + (uA.x + nA.x), g4 * a.x);
            oA.y = fmaf(f, (a.x + a.z) + (uA.y + nA.y), g4 * a.y);
            oA.z = fmaf(f, (a.y + a.w) + (uA.z + nA.z), g4 * a.z);
            oA.w = fmaf(f, (a.z + q.x) + (uA.w + nA.w), g4 * a.w);
            oB.x = fmaf(f, (a.w + q.y) + (uB.x + nB.x), g4 * q.x);
            oB.y = fmaf(f, (q.x + q.z) + (uB.y + nB.y), g4 * q.y);
            oB.z = fmaf(f, (q.y + q.w) + (uB.z + nB.z), g4 * q.z);
            oB.w = fmaf(f, (q.z + R  ) + (uB.w + nB.w), g4 * q.w);
            cA[j] = oA;
            cB[j] = oB;
            uA = a;
            uB = q;
        }
        __syncthreads();    // halo reads of this step complete
        if (act) {
            *(float4*)(&pub[2 * s + 1][cb])     = cA[0];
            *(float4*)(&pub[2 * s + 1][cb + 4]) = cB[0];
            *(float4*)(&pub[2 * s + 2][cb])     = cA[5];
            *(float4*)(&pub[2 * s + 2][cb + 4]) = cB[5];
        }
        __syncthreads();    // halo writes visible for next step
    }

    // ---- write output: local rows [9,137), col groups 1..8 ----
    if (act && g >= 1 && g < 9) {
        float* db = dstp + (size_t)b * HW;
        const int gcol = w0 - 8 + cb;        // in [w0, w0+56]
#pragma unroll
        for (int j = 0; j < 6; j++) {
            const int lr = r1 + j;
            if (lr >= 9 && lr < 137) {
                float* p = db + (size_t)(h0 + lr - 9) * WW + gcol;
                float4 a = cA[j], q = cB[j];
                if (finish) { a = clamp4(a); q = clamp4(q); }
                *(float4*)p       = a;
                *(float4*)(p + 4) = q;
            }
        }
    }
}

extern "C" void kernel_launch(void* const* d_in, const int* in_sizes, int n_in,
                              void* d_out, int out_size, void* d_ws, size_t ws_size,
                              hipStream_t stream) {
    const float* x     = (const float*)d_in[0];
    const int*   t     = (const int*)d_in[1];
    const float* dcoef = (const float*)d_in[2];
    float* out = (float*)d_out;

    // ws layout (header 4 KiB): [partials: 32*16 floats][f1 @ 4 KiB: 32 MiB]
    float* partials = (float*)d_ws;
    float* f1       = (float*)((char*)d_ws + 4096);

    reduce_x_kernel<<<dim3(RBLK, BB), dim3(256), 0, stream>>>(x, t, partials);

    // Chain x -> f1 -> out; finishing samples always write out
    // (src never aliases out -> no hazard, no fix-up pass).
    fused_kernel<<<dim3(32, BB), dim3(256), 0, stream>>>(x,  f1, out, x, out, t, partials, dcoef, 0);
    fused_kernel<<<dim3(32, BB), dim3(256), 0, stream>>>(f1, f1, out, x, out, t, partials, dcoef, 8);
}